// Round 10
// baseline (214.219 us; speedup 1.0000x reference)
//
#include <hip/hip_runtime.h>
#include <hip/hip_bf16.h>

#define D 128
#define NN 40000
#define EE 640000
#define GG 8
#define NPG 5000
#define CSUB 16         // slots per (node, e&7) bucket; load ~ Poisson(2)
#define NBKT 8
#define OVCAP 4095
#define REP 32          // stats replica buffers

using short8 = __attribute__((ext_vector_type(8))) short;  // 8 bf16 (4 VGPRs)
using f32x4 = __attribute__((ext_vector_type(4))) float;   // MFMA accumulator

__device__ __forceinline__ float lrelu(float v) { return v >= 0.f ? v : 0.01f * v; }

__device__ __forceinline__ ushort f2bf(float f) {  // RNE fp32 -> bf16 bits
    union { float f; uint u; } c; c.f = f;
    return (ushort)((c.u + 0x7FFFu + ((c.u >> 16) & 1u)) >> 16);
}
__device__ __forceinline__ float bf2f_lo(uint u) { union { uint u; float f; } c; c.u = u << 16; return c.f; }
__device__ __forceinline__ float bf2f_hi(uint u) { union { uint u; float f; } c; c.u = u & 0xFFFF0000u; return c.f; }

// ---------------------------------------------------------------------------
// prep: blocks 0-3 transpose weights to bf16 W^T; blocks 4+ zero
// {statsR | statsF | deg8 | ov}.
// ---------------------------------------------------------------------------
__global__ __launch_bounds__(256) void prep_k(const float* __restrict__ W1,
                                              const float* __restrict__ W2,
                                              const float* __restrict__ Wo,
                                              const float* __restrict__ Wn,
                                              short* __restrict__ WT,
                                              uint4* __restrict__ zbase, int zlen16) {
    const int b = blockIdx.x;
    if (b < 4) {
        const float* W = b == 0 ? W1 : b == 1 ? W2 : b == 2 ? Wo : Wn;
        short* T = WT + b * (D * D);
#pragma unroll 4
        for (int i = 0; i < 64; ++i) {
            int flat = threadIdx.x + i * 256;
            int k = flat >> 7, n = flat & 127;
            T[n * D + k] = (short)f2bf(W[flat]);
        }
    } else {
        int idx = (b - 4) * 256 + threadIdx.x;
        if (idx < zlen16) zbase[idx] = uint4{0, 0, 0, 0};
    }
}

// ---------------------------------------------------------------------------
// MFMA helpers. B staged in LDS Bs[128][136]; A-fragments DIRECT from global
// (lanes l,l+16,l+32,l+48 cover one 64B line of a row -> fully coalesced).
// ---------------------------------------------------------------------------
__device__ __forceinline__ void stage_B(const short* __restrict__ WT,
                                        short (*Bs)[136], int tid) {
    const uint4* bsrc = (const uint4*)WT;
#pragma unroll
    for (int i = 0; i < 8; ++i) {
        int idx = tid + i * 256;
        int flat = idx * 8;
        *(uint4*)&Bs[flat >> 7][flat & 127] = bsrc[idx];
    }
}

__device__ __forceinline__ void mfma8(const short8 (&a)[4], short (*Bs)[136],
                                      f32x4 (&acc)[8], int lrow, int kgrp) {
#pragma unroll
    for (int ks = 0; ks < 4; ++ks) {
        const int kb = ks * 32 + kgrp;
#pragma unroll
        for (int nt = 0; nt < 8; ++nt) {
            short8 b = *(const short8*)&Bs[nt * 16 + lrow][kb];
            acc[nt] = __builtin_amdgcn_mfma_f32_16x16x32_bf16(a[ks], b, acc[nt], 0, 0, 0);
        }
    }
}

// Fused MLP: h = leaky(x@W1) @ W2. A1 direct from global fp32 (converted in
// reg); t1 handoff via per-wave LDS bounce tw (no extra barrier). 3 barriers.
__global__ __launch_bounds__(256) void mlp_k(const float* __restrict__ x,
                                             const short* __restrict__ W1T,
                                             const short* __restrict__ W2T,
                                             ushort* __restrict__ h) {
    __shared__ short Bs[128][136];
    __shared__ short tw[4][16][136];
    const int tid = threadIdx.x;
    const int wv = tid >> 6, lane = tid & 63;
    const int lrow = lane & 15, kgrp = (lane >> 4) * 8;
    const int m0 = wv * 16;
    const int arow = blockIdx.x * 64;
    short8 a[4];
#pragma unroll
    for (int ks = 0; ks < 4; ++ks) {
        const float* xp = &x[(size_t)(arow + m0 + lrow) * D + ks * 32 + kgrp];
        const float4 u0 = *(const float4*)xp;
        const float4 u1 = *(const float4*)(xp + 4);
        short8 aa;
        aa[0] = (short)f2bf(u0.x); aa[1] = (short)f2bf(u0.y);
        aa[2] = (short)f2bf(u0.z); aa[3] = (short)f2bf(u0.w);
        aa[4] = (short)f2bf(u1.x); aa[5] = (short)f2bf(u1.y);
        aa[6] = (short)f2bf(u1.z); aa[7] = (short)f2bf(u1.w);
        a[ks] = aa;
    }
    stage_B(W1T, Bs, tid);
    __syncthreads();
    f32x4 acc[8] = {};
    mfma8(a, Bs, acc, lrow, kgrp);
    // t1 -> per-wave LDS (C-layout -> A-layout transpose within the wave)
    const int c0 = lane & 15;
    const int rg = (lane >> 4) * 4;
#pragma unroll
    for (int nt = 0; nt < 8; ++nt)
#pragma unroll
        for (int r = 0; r < 4; ++r)
            tw[wv][rg + r][nt * 16 + c0] = (short)f2bf(lrelu(acc[nt][r]));
    __syncthreads();                 // all waves done reading Bs(W1)
    stage_B(W2T, Bs, tid);
#pragma unroll
    for (int ks = 0; ks < 4; ++ks)
        a[ks] = *(const short8*)&tw[wv][lrow][ks * 32 + kgrp];
#pragma unroll
    for (int nt = 0; nt < 8; ++nt) acc[nt] = f32x4{0.f, 0.f, 0.f, 0.f};
    __syncthreads();                 // Bs(W2) ready
    mfma8(a, Bs, acc, lrow, kgrp);
#pragma unroll
    for (int nt = 0; nt < 8; ++nt)
#pragma unroll
        for (int r = 0; r < 4; ++r)
            h[(size_t)(arow + m0 + rg + r) * D + nt * 16 + c0] = f2bf(acc[nt][r]);
}

// ---------------------------------------------------------------------------
// CSR build: 4 edges/thread, 8-way split counters deg8[n*8 + (e&7)]
// (interleaved: line = 2 nodes => ~32 RMW/line).
// ---------------------------------------------------------------------------
__global__ __launch_bounds__(256) void fill_k(const int* __restrict__ ei,
                                              const float* __restrict__ w,
                                              int* __restrict__ deg8,
                                              int2* __restrict__ csr,
                                              int* __restrict__ ov) {
    const int t = blockIdx.x * 256 + threadIdx.x;   // EE/4 threads
    const int e0 = t * 4;
    const int kbase = (t & 1) * 4;                   // e0 & 7 = 4*(t&1)
    const int4 dst = *(const int4*)&ei[e0];
    const int4 src = *(const int4*)&ei[EE + e0];
    const float4 wv = *(const float4*)&w[e0];
    const int ds[4] = {dst.x, dst.y, dst.z, dst.w};
    const int sr[4] = {src.x, src.y, src.z, src.w};
    const float wf[4] = {wv.x, wv.y, wv.z, wv.w};
    int pos[4];
#pragma unroll
    for (int j = 0; j < 4; ++j)
        pos[j] = atomicAdd(&deg8[ds[j] * NBKT + kbase + j], 1);
#pragma unroll
    for (int j = 0; j < 4; ++j) {
        if (pos[j] < CSUB) {
            csr[(size_t)ds[j] * (NBKT * CSUB) + (kbase + j) * CSUB + pos[j]] =
                make_int2(sr[j], __float_as_int(wf[j]));
        } else {
            const int oi = atomicAdd(&ov[0], 1);
            if (oi < OVCAP) ov[1 + oi] = e0 + j;
        }
    }
}

// gather: quarter-wave (16 lanes x uint4) per node, 16-deep batched loads.
// fp32 sum -> leaky -> one bf16 rounding -> xnact.
__global__ __launch_bounds__(256) void gather_k(const ushort* __restrict__ h,
                                                const int* __restrict__ deg8,
                                                const int2* __restrict__ csr,
                                                const int* __restrict__ ei,
                                                const float* __restrict__ w,
                                                const int* __restrict__ ov,
                                                ushort* __restrict__ xnact) {
    const int n = blockIdx.x * 16 + (threadIdx.x >> 4);
    const int lane = threadIdx.x & 15;
    const int4 da = *(const int4*)&deg8[n * NBKT];
    const int4 db = *(const int4*)&deg8[n * NBKT + 4];
    const int b0 = min(da.x, CSUB);
    const int b1 = b0 + min(da.y, CSUB);
    const int b2 = b1 + min(da.z, CSUB);
    const int b3 = b2 + min(da.w, CSUB);
    const int b4 = b3 + min(db.x, CSUB);
    const int b5 = b4 + min(db.y, CSUB);
    const int b6 = b5 + min(db.z, CSUB);
    const int total = b6 + min(db.w, CSUB);
    const int2* row = csr + (size_t)n * (NBKT * CSUB);
    auto slot = [&](int jj) -> int {
        return jj < b0 ? jj
             : jj < b1 ? jj - b0 + 16
             : jj < b2 ? jj - b1 + 32
             : jj < b3 ? jj - b2 + 48
             : jj < b4 ? jj - b3 + 64
             : jj < b5 ? jj - b4 + 80
             : jj < b6 ? jj - b5 + 96
             :           jj - b6 + 112;
    };
    float acc[8] = {};
    int j = 0;
#define GBODY(NB)                                                              \
    {                                                                          \
        int2 p[NB]; uint4 v[NB];                                               \
        _Pragma("unroll") for (int t = 0; t < NB; ++t) p[t] = row[slot(j + t)];\
        _Pragma("unroll") for (int t = 0; t < NB; ++t)                         \
            v[t] = *((const uint4*)(h + (size_t)p[t].x * D) + lane);           \
        _Pragma("unroll") for (int t = 0; t < NB; ++t) {                       \
            const float wv = __int_as_float(p[t].y);                           \
            acc[0] += wv * bf2f_lo(v[t].x); acc[1] += wv * bf2f_hi(v[t].x);    \
            acc[2] += wv * bf2f_lo(v[t].y); acc[3] += wv * bf2f_hi(v[t].y);    \
            acc[4] += wv * bf2f_lo(v[t].z); acc[5] += wv * bf2f_hi(v[t].z);    \
            acc[6] += wv * bf2f_lo(v[t].w); acc[7] += wv * bf2f_hi(v[t].w);    \
        }                                                                      \
        j += NB;                                                               \
    }
    while (j + 16 <= total) GBODY(16)
    while (j + 4 <= total) GBODY(4)
    for (; j < total; ++j) {
        const int2 p = row[slot(j)];
        const uint4 v = *((const uint4*)(h + (size_t)p.x * D) + lane);
        const float wv = __int_as_float(p.y);
        acc[0] += wv * bf2f_lo(v.x); acc[1] += wv * bf2f_hi(v.x);
        acc[2] += wv * bf2f_lo(v.y); acc[3] += wv * bf2f_hi(v.y);
        acc[4] += wv * bf2f_lo(v.z); acc[5] += wv * bf2f_hi(v.z);
        acc[6] += wv * bf2f_lo(v.w); acc[7] += wv * bf2f_hi(v.w);
    }
#undef GBODY
    if (da.x > CSUB || da.y > CSUB || da.z > CSUB || da.w > CSUB ||
        db.x > CSUB || db.y > CSUB || db.z > CSUB || db.w > CSUB) {  // ~never
        const int cnt = min(ov[0], OVCAP);
        for (int i = 0; i < cnt; ++i) {
            const int e = ov[1 + i];
            if (ei[e] == n) {
                const float wv = w[e];
                const uint4 v = *((const uint4*)(h + (size_t)ei[EE + e] * D) + lane);
                acc[0] += wv * bf2f_lo(v.x); acc[1] += wv * bf2f_hi(v.x);
                acc[2] += wv * bf2f_lo(v.y); acc[3] += wv * bf2f_hi(v.y);
                acc[4] += wv * bf2f_lo(v.z); acc[5] += wv * bf2f_hi(v.z);
                acc[6] += wv * bf2f_lo(v.w); acc[7] += wv * bf2f_hi(v.w);
            }
        }
    }
    uint4 st;
    st.x = (uint)f2bf(lrelu(acc[0])) | ((uint)f2bf(lrelu(acc[1])) << 16);
    st.y = (uint)f2bf(lrelu(acc[2])) | ((uint)f2bf(lrelu(acc[3])) << 16);
    st.z = (uint)f2bf(lrelu(acc[4])) | ((uint)f2bf(lrelu(acc[5])) << 16);
    st.w = (uint)f2bf(lrelu(acc[6])) | ((uint)f2bf(lrelu(acc[7])) << 16);
    *((uint4*)(xnact + (size_t)n * D) + lane) = st;
}

// ---------------------------------------------------------------------------
// out = h@Wo + xn_act@Wn, fused stats epilogue into REP replica buffers.
// A-fragments direct from global (bf16). 4 barriers, 51.7 KB LDS.
// ---------------------------------------------------------------------------
__global__ __launch_bounds__(256) void mmstats_k(const ushort* __restrict__ h,
                                                 const short* __restrict__ WoT,
                                                 const ushort* __restrict__ xa,
                                                 const short* __restrict__ WnT,
                                                 float* __restrict__ out,
                                                 float* __restrict__ statsR) {
    __shared__ short Bs[128][136];
    __shared__ float ls[2][16][132];
    const int tid = threadIdx.x;
    const int wv = tid >> 6, lane = tid & 63;
    const int lrow = lane & 15, kgrp = (lane >> 4) * 8;
    const int m0 = wv * 16;
    const int arow = blockIdx.x * 64;
    short8 a[4];
#pragma unroll
    for (int ks = 0; ks < 4; ++ks)
        a[ks] = *(const short8*)&h[(size_t)(arow + m0 + lrow) * D + ks * 32 + kgrp];
    stage_B(WoT, Bs, tid);
    __syncthreads();
    f32x4 acc[8] = {};
    mfma8(a, Bs, acc, lrow, kgrp);
#pragma unroll
    for (int ks = 0; ks < 4; ++ks)
        a[ks] = *(const short8*)&xa[(size_t)(arow + m0 + lrow) * D + ks * 32 + kgrp];
    __syncthreads();                 // all waves done reading Bs(Wo)
    stage_B(WnT, Bs, tid);
    __syncthreads();                 // Bs(Wn) ready
    mfma8(a, Bs, acc, lrow, kgrp);
    // epilogue: C write + per-column partial stats
    const int c0 = lane & 15;
    const int rg = (lane >> 4) * 4;
    const int li = wv * 4 + (lane >> 4);
#pragma unroll
    for (int nt = 0; nt < 8; ++nt) {
        float s = 0.f, q = 0.f;
#pragma unroll
        for (int r = 0; r < 4; ++r) {
            const float v = acc[nt][r];
            out[(size_t)(arow + m0 + rg + r) * D + nt * 16 + c0] = v;
            s += v; q += v * v;
        }
        ls[0][li][nt * 16 + c0] = s;
        ls[1][li][nt * 16 + c0] = q;
    }
    __syncthreads();
    if (tid < 128) {
        const int g0 = arow / NPG;
        const int gsplit = (g0 + 1) * NPG - arow;  // rows in g0; %4==0
        float s0 = 0.f, q0 = 0.f, s1 = 0.f, q1 = 0.f;
#pragma unroll
        for (int i = 0; i < 16; ++i) {
            const float sv = ls[0][i][tid];
            const float qv = ls[1][i][tid];
            if (i * 4 >= gsplit) { s1 += sv; q1 += qv; }
            else { s0 += sv; q0 += qv; }
        }
        const int rep = blockIdx.x & (REP - 1);
        float* S = &statsR[(size_t)rep * (2 * GG * D) + 0 * GG * D + g0 * D + tid];
        float* Q = &statsR[(size_t)rep * (2 * GG * D) + 1 * GG * D + g0 * D + tid];
        atomicAdd(S, s0);
        atomicAdd(Q, q0);
        if (gsplit < 64) { atomicAdd(S + D, s1); atomicAdd(Q + D, q1); }
    }
}

// reduce the REP replicas -> statsF[2][GG][D]
__global__ __launch_bounds__(256) void reduce_k(const float* __restrict__ statsR,
                                                float* __restrict__ statsF) {
    const int idx = blockIdx.x * 256 + threadIdx.x;  // 0..2047
    float s = 0.f;
#pragma unroll
    for (int rep = 0; rep < REP; ++rep) s += statsR[rep * (2 * GG * D) + idx];
    statsF[idx] = s;
}

__global__ __launch_bounds__(256) void norm_k(float* __restrict__ out,
                                              const float* __restrict__ statsF,
                                              const float* __restrict__ gamma,
                                              const float* __restrict__ beta) {
    const int i4 = blockIdx.x * 256 + threadIdx.x;  // over NN*D/4
    const int row = i4 >> 5;
    const int g = row / NPG;
    const int d0 = (i4 & 31) * 4;
    float4 v = *((float4*)out + i4);
    const float4 s4 = *(const float4*)&statsF[g * D + d0];
    const float4 q4 = *(const float4*)&statsF[GG * D + g * D + d0];
    const float4 g4 = *(const float4*)&gamma[d0];
    const float4 b4 = *(const float4*)&beta[d0];
    const float inv = 1.f / (float)NPG;
    const float invm1 = 1.f / (float)(NPG - 1);
    float mu, var, sg;
    mu = s4.x * inv; var = (q4.x - s4.x * mu) * invm1; sg = sqrtf(fmaxf(var, 0.f));
    v.x = (v.x - mu) / (sg + 1e-6f) * g4.x + b4.x;
    mu = s4.y * inv; var = (q4.y - s4.y * mu) * invm1; sg = sqrtf(fmaxf(var, 0.f));
    v.y = (v.y - mu) / (sg + 1e-6f) * g4.y + b4.y;
    mu = s4.z * inv; var = (q4.z - s4.z * mu) * invm1; sg = sqrtf(fmaxf(var, 0.f));
    v.z = (v.z - mu) / (sg + 1e-6f) * g4.z + b4.z;
    mu = s4.w * inv; var = (q4.w - s4.w * mu) * invm1; sg = sqrtf(fmaxf(var, 0.f));
    v.w = (v.w - mu) / (sg + 1e-6f) * g4.w + b4.w;
    *((float4*)out + i4) = v;
}

extern "C" void kernel_launch(void* const* d_in, const int* in_sizes, int n_in,
                              void* d_out, int out_size, void* d_ws, size_t ws_size,
                              hipStream_t stream) {
    const float* x = (const float*)d_in[0];
    const int* ei = (const int*)d_in[1];
    const float* w = (const float*)d_in[2];
    const float* W1 = (const float*)d_in[5];
    const float* W2 = (const float*)d_in[6];
    const float* Wo = (const float*)d_in[7];
    const float* Wn = (const float*)d_in[8];
    const float* gamma = (const float*)d_in[9];
    const float* beta = (const float*)d_in[10];
    float* out = (float*)d_out;

    char* ws = (char*)d_ws;
    const size_t BF16MAT = (size_t)NN * D * 2;        // 10,240,000
    size_t off = 0;
    ushort* h = (ushort*)(ws + off);      off += BF16MAT;
    ushort* xnact = (ushort*)(ws + off);  off += BF16MAT;
    const size_t ZOFF = off;                                  // zero region
    float* statsR = (float*)(ws + off);   off += (size_t)REP * 2 * GG * D * 4;  // 262,144
    float* statsF = (float*)(ws + off);   off += 2 * GG * D * 4;                // 8,192
    int* deg8 = (int*)(ws + off);         off += (size_t)NN * NBKT * 4;         // 1,280,000
    int* ov = (int*)(ws + off);           off += (1 + OVCAP) * 4;               // 16,384
    const int ZLEN16 = (int)((off - ZOFF) / 16);              // 97,920
    short* WT = (short*)(ws + off);       off += 4 * (size_t)D * D * 2;         // 131,072
    int2* csr = (int2*)(ws + off);        // NN*128*8 = 40,960,000; total ~63 MB

    prep_k<<<4 + (ZLEN16 + 255) / 256, 256, 0, stream>>>(W1, W2, Wo, Wn, WT,
                                                         (uint4*)(ws + ZOFF), ZLEN16);
    mlp_k<<<NN / 64, 256, 0, stream>>>(x, WT, WT + D * D, h);
    fill_k<<<EE / (256 * 4), 256, 0, stream>>>(ei, w, deg8, csr, ov);
    gather_k<<<NN / 16, 256, 0, stream>>>(h, deg8, csr, ei, w, ov, xnact);
    mmstats_k<<<NN / 64, 256, 0, stream>>>(h, WT + 2 * D * D, xnact, WT + 3 * D * D, out, statsR);
    reduce_k<<<(2 * GG * D) / 256, 256, 0, stream>>>(statsR, statsF);
    norm_k<<<(NN * D / 4) / 256, 256, 0, stream>>>(out, statsF, gamma, beta);
}

// Round 13
// 193.922 us; speedup vs baseline: 1.1047x; 1.1047x over previous
//
#include <hip/hip_runtime.h>
#include <hip/hip_bf16.h>

#define D 128
#define NN 40000
#define EE 640000
#define GG 8
#define NPG 5000
#define CSUB 16         // slots per (node, e&3) bucket; load ~ Poisson(4)
#define OVCAP 4095
#define REP 32          // stats replica buffers

using short8 = __attribute__((ext_vector_type(8))) short;  // 8 bf16 (4 VGPRs)
using f32x4 = __attribute__((ext_vector_type(4))) float;   // MFMA accumulator

__device__ __forceinline__ float lrelu(float v) { return v >= 0.f ? v : 0.01f * v; }

__device__ __forceinline__ ushort f2bf(float f) {  // RNE fp32 -> bf16 bits
    union { float f; uint u; } c; c.f = f;
    return (ushort)((c.u + 0x7FFFu + ((c.u >> 16) & 1u)) >> 16);
}
__device__ __forceinline__ float bf2f_lo(uint u) { union { uint u; float f; } c; c.u = u << 16; return c.f; }
__device__ __forceinline__ float bf2f_hi(uint u) { union { uint u; float f; } c; c.u = u & 0xFFFF0000u; return c.f; }

// ---------------------------------------------------------------------------
// prep: blocks 0-3 transpose weights to bf16 W^T; blocks 4+ zero
// {statsR | statsF | deg4 | ov}.
// ---------------------------------------------------------------------------
__global__ __launch_bounds__(256) void prep_k(const float* __restrict__ W1,
                                              const float* __restrict__ W2,
                                              const float* __restrict__ Wo,
                                              const float* __restrict__ Wn,
                                              short* __restrict__ WT,
                                              uint4* __restrict__ zbase, int zlen16) {
    const int b = blockIdx.x;
    if (b < 4) {
        const float* W = b == 0 ? W1 : b == 1 ? W2 : b == 2 ? Wo : Wn;
        short* T = WT + b * (D * D);
#pragma unroll 4
        for (int i = 0; i < 64; ++i) {
            int flat = threadIdx.x + i * 256;
            int k = flat >> 7, n = flat & 127;
            T[n * D + k] = (short)f2bf(W[flat]);
        }
    } else {
        int idx = (b - 4) * 256 + threadIdx.x;
        if (idx < zlen16) zbase[idx] = uint4{0, 0, 0, 0};
    }
}

// ---------------------------------------------------------------------------
// MFMA helpers. B staged in LDS Bs[128][136]; A-fragments DIRECT from global.
// ---------------------------------------------------------------------------
__device__ __forceinline__ void stage_B(const short* __restrict__ WT,
                                        short (*Bs)[136], int tid) {
    const uint4* bsrc = (const uint4*)WT;
#pragma unroll
    for (int i = 0; i < 8; ++i) {
        int idx = tid + i * 256;
        int flat = idx * 8;
        *(uint4*)&Bs[flat >> 7][flat & 127] = bsrc[idx];
    }
}

__device__ __forceinline__ void mfma8(const short8 (&a)[4], short (*Bs)[136],
                                      f32x4 (&acc)[8], int lrow, int kgrp) {
#pragma unroll
    for (int ks = 0; ks < 4; ++ks) {
        const int kb = ks * 32 + kgrp;
#pragma unroll
        for (int nt = 0; nt < 8; ++nt) {
            short8 b = *(const short8*)&Bs[nt * 16 + lrow][kb];
            acc[nt] = __builtin_amdgcn_mfma_f32_16x16x32_bf16(a[ks], b, acc[nt], 0, 0, 0);
        }
    }
}

// ---------------------------------------------------------------------------
// FUSED: blocks [0,625) = MLP  h = leaky(x@W1)@W2 ;  blocks [625,1250) = CSR
// build (independent inputs -> fill hides under mlp).
// ---------------------------------------------------------------------------
__global__ __launch_bounds__(256) void mlpfill_k(const float* __restrict__ x,
                                                 const short* __restrict__ W1T,
                                                 const short* __restrict__ W2T,
                                                 ushort* __restrict__ h,
                                                 const int* __restrict__ ei,
                                                 const float* __restrict__ w,
                                                 int* __restrict__ deg4,
                                                 int2* __restrict__ csr,
                                                 int* __restrict__ ov) {
    __shared__ short Bs[128][136];
    __shared__ short tw[4][16][136];
    const int tid = threadIdx.x;
    if (blockIdx.x < NN / 64) {
        // ---------------- MLP path ----------------
        const int wv = tid >> 6, lane = tid & 63;
        const int lrow = lane & 15, kgrp = (lane >> 4) * 8;
        const int m0 = wv * 16;
        const int arow = blockIdx.x * 64;
        short8 a[4];
#pragma unroll
        for (int ks = 0; ks < 4; ++ks) {
            const float* xp = &x[(size_t)(arow + m0 + lrow) * D + ks * 32 + kgrp];
            const float4 u0 = *(const float4*)xp;
            const float4 u1 = *(const float4*)(xp + 4);
            short8 aa;
            aa[0] = (short)f2bf(u0.x); aa[1] = (short)f2bf(u0.y);
            aa[2] = (short)f2bf(u0.z); aa[3] = (short)f2bf(u0.w);
            aa[4] = (short)f2bf(u1.x); aa[5] = (short)f2bf(u1.y);
            aa[6] = (short)f2bf(u1.z); aa[7] = (short)f2bf(u1.w);
            a[ks] = aa;
        }
        stage_B(W1T, Bs, tid);
        __syncthreads();
        f32x4 acc[8] = {};
        mfma8(a, Bs, acc, lrow, kgrp);
        const int c0 = lane & 15;
        const int rg = (lane >> 4) * 4;
#pragma unroll
        for (int nt = 0; nt < 8; ++nt)
#pragma unroll
            for (int r = 0; r < 4; ++r)
                tw[wv][rg + r][nt * 16 + c0] = (short)f2bf(lrelu(acc[nt][r]));
        __syncthreads();                 // all waves done reading Bs(W1)
        stage_B(W2T, Bs, tid);
#pragma unroll
        for (int ks = 0; ks < 4; ++ks)
            a[ks] = *(const short8*)&tw[wv][lrow][ks * 32 + kgrp];
#pragma unroll
        for (int nt = 0; nt < 8; ++nt) acc[nt] = f32x4{0.f, 0.f, 0.f, 0.f};
        __syncthreads();                 // Bs(W2) ready
        mfma8(a, Bs, acc, lrow, kgrp);
#pragma unroll
        for (int nt = 0; nt < 8; ++nt)
#pragma unroll
            for (int r = 0; r < 4; ++r)
                h[(size_t)(arow + m0 + rg + r) * D + nt * 16 + c0] = f2bf(acc[nt][r]);
    } else {
        // ---------------- fill path: 4 edges/thread, deg4[k*NN+dst] ----------------
        const int t = (blockIdx.x - NN / 64) * 256 + tid;   // EE/4 threads
        const int e0 = t * 4;
        const int4 dst = *(const int4*)&ei[e0];
        const int4 src = *(const int4*)&ei[EE + e0];
        const float4 wv4 = *(const float4*)&w[e0];
        const int ds[4] = {dst.x, dst.y, dst.z, dst.w};
        const int sr[4] = {src.x, src.y, src.z, src.w};
        const float wf[4] = {wv4.x, wv4.y, wv4.z, wv4.w};
        int pos[4];
#pragma unroll
        for (int k = 0; k < 4; ++k) pos[k] = atomicAdd(&deg4[k * NN + ds[k]], 1);
#pragma unroll
        for (int k = 0; k < 4; ++k) {
            if (pos[k] < CSUB) {
                csr[(size_t)ds[k] * 64 + k * CSUB + pos[k]] = make_int2(sr[k], __float_as_int(wf[k]));
            } else {
                const int oi = atomicAdd(&ov[0], 1);
                if (oi < OVCAP) ov[1 + oi] = e0 + k;
            }
        }
    }
}

// ---------------------------------------------------------------------------
// gather: quarter-wave (16 lanes x uint4) per node, 8-deep batched loads,
// 4-bucket flatten (round-8 proven). fp32 sum -> leaky -> bf16 xnact.
// ---------------------------------------------------------------------------
__global__ __launch_bounds__(256) void gather_k(const ushort* __restrict__ h,
                                                const int* __restrict__ deg4,
                                                const int2* __restrict__ csr,
                                                const int* __restrict__ ei,
                                                const float* __restrict__ w,
                                                const int* __restrict__ ov,
                                                ushort* __restrict__ xnact) {
    const int n = blockIdx.x * 16 + (threadIdx.x >> 4);
    const int lane = threadIdx.x & 15;
    const int d0 = deg4[0 * NN + n], d1 = deg4[1 * NN + n];
    const int d2 = deg4[2 * NN + n], d3 = deg4[3 * NN + n];
    const int c0 = min(d0, CSUB), c1 = min(d1, CSUB);
    const int c2 = min(d2, CSUB), c3 = min(d3, CSUB);
    const int t0 = c0, t1 = t0 + c1, t2 = t1 + c2;
    const int total = t2 + c3;
    const int2* row = csr + (size_t)n * 64;
    float acc[8] = {};
    int j = 0;
    for (; j + 8 <= total; j += 8) {
        int2 p[8]; uint4 v[8];
#pragma unroll
        for (int t = 0; t < 8; ++t) {
            const int jj = j + t;
            const int s = jj < t0 ? jj
                        : jj < t1 ? jj - t0 + CSUB
                        : jj < t2 ? jj - t1 + 2 * CSUB
                                  : jj - t2 + 3 * CSUB;
            p[t] = row[s];
        }
#pragma unroll
        for (int t = 0; t < 8; ++t) v[t] = *((const uint4*)(h + (size_t)p[t].x * D) + lane);
#pragma unroll
        for (int t = 0; t < 8; ++t) {
            const float wv = __int_as_float(p[t].y);
            acc[0] += wv * bf2f_lo(v[t].x); acc[1] += wv * bf2f_hi(v[t].x);
            acc[2] += wv * bf2f_lo(v[t].y); acc[3] += wv * bf2f_hi(v[t].y);
            acc[4] += wv * bf2f_lo(v[t].z); acc[5] += wv * bf2f_hi(v[t].z);
            acc[6] += wv * bf2f_lo(v[t].w); acc[7] += wv * bf2f_hi(v[t].w);
        }
    }
    if (j + 4 <= total) {
        int2 p[4]; uint4 v[4];
#pragma unroll
        for (int t = 0; t < 4; ++t) {
            const int jj = j + t;
            const int s = jj < t0 ? jj
                        : jj < t1 ? jj - t0 + CSUB
                        : jj < t2 ? jj - t1 + 2 * CSUB
                                  : jj - t2 + 3 * CSUB;
            p[t] = row[s];
        }
#pragma unroll
        for (int t = 0; t < 4; ++t) v[t] = *((const uint4*)(h + (size_t)p[t].x * D) + lane);
#pragma unroll
        for (int t = 0; t < 4; ++t) {
            const float wv = __int_as_float(p[t].y);
            acc[0] += wv * bf2f_lo(v[t].x); acc[1] += wv * bf2f_hi(v[t].x);
            acc[2] += wv * bf2f_lo(v[t].y); acc[3] += wv * bf2f_hi(v[t].y);
            acc[4] += wv * bf2f_lo(v[t].z); acc[5] += wv * bf2f_hi(v[t].z);
            acc[6] += wv * bf2f_lo(v[t].w); acc[7] += wv * bf2f_hi(v[t].w);
        }
        j += 4;
    }
    for (; j < total; ++j) {
        const int s = j < t0 ? j
                    : j < t1 ? j - t0 + CSUB
                    : j < t2 ? j - t1 + 2 * CSUB
                             : j - t2 + 3 * CSUB;
        const int2 p = row[s];
        const uint4 v = *((const uint4*)(h + (size_t)p.x * D) + lane);
        const float wv = __int_as_float(p.y);
        acc[0] += wv * bf2f_lo(v.x); acc[1] += wv * bf2f_hi(v.x);
        acc[2] += wv * bf2f_lo(v.y); acc[3] += wv * bf2f_hi(v.y);
        acc[4] += wv * bf2f_lo(v.z); acc[5] += wv * bf2f_hi(v.z);
        acc[6] += wv * bf2f_lo(v.w); acc[7] += wv * bf2f_hi(v.w);
    }
    if (d0 > CSUB || d1 > CSUB || d2 > CSUB || d3 > CSUB) {  // ~never (P~1e-7)
        const int cnt = min(ov[0], OVCAP);
        for (int i = 0; i < cnt; ++i) {
            const int e = ov[1 + i];
            if (ei[e] == n) {
                const float wv = w[e];
                const uint4 v = *((const uint4*)(h + (size_t)ei[EE + e] * D) + lane);
                acc[0] += wv * bf2f_lo(v.x); acc[1] += wv * bf2f_hi(v.x);
                acc[2] += wv * bf2f_lo(v.y); acc[3] += wv * bf2f_hi(v.y);
                acc[4] += wv * bf2f_lo(v.z); acc[5] += wv * bf2f_hi(v.z);
                acc[6] += wv * bf2f_lo(v.w); acc[7] += wv * bf2f_hi(v.w);
            }
        }
    }
    uint4 st;
    st.x = (uint)f2bf(lrelu(acc[0])) | ((uint)f2bf(lrelu(acc[1])) << 16);
    st.y = (uint)f2bf(lrelu(acc[2])) | ((uint)f2bf(lrelu(acc[3])) << 16);
    st.z = (uint)f2bf(lrelu(acc[4])) | ((uint)f2bf(lrelu(acc[5])) << 16);
    st.w = (uint)f2bf(lrelu(acc[6])) | ((uint)f2bf(lrelu(acc[7])) << 16);
    *((uint4*)(xnact + (size_t)n * D) + lane) = st;
}

// ---------------------------------------------------------------------------
// out = h@Wo + xn_act@Wn, fused stats epilogue into REP replica buffers.
// ---------------------------------------------------------------------------
__global__ __launch_bounds__(256) void mmstats_k(const ushort* __restrict__ h,
                                                 const short* __restrict__ WoT,
                                                 const ushort* __restrict__ xa,
                                                 const short* __restrict__ WnT,
                                                 float* __restrict__ out,
                                                 float* __restrict__ statsR) {
    __shared__ short Bs[128][136];
    __shared__ float ls[2][16][132];
    const int tid = threadIdx.x;
    const int wv = tid >> 6, lane = tid & 63;
    const int lrow = lane & 15, kgrp = (lane >> 4) * 8;
    const int m0 = wv * 16;
    const int arow = blockIdx.x * 64;
    short8 a[4];
#pragma unroll
    for (int ks = 0; ks < 4; ++ks)
        a[ks] = *(const short8*)&h[(size_t)(arow + m0 + lrow) * D + ks * 32 + kgrp];
    stage_B(WoT, Bs, tid);
    __syncthreads();
    f32x4 acc[8] = {};
    mfma8(a, Bs, acc, lrow, kgrp);
#pragma unroll
    for (int ks = 0; ks < 4; ++ks)
        a[ks] = *(const short8*)&xa[(size_t)(arow + m0 + lrow) * D + ks * 32 + kgrp];
    __syncthreads();                 // all waves done reading Bs(Wo)
    stage_B(WnT, Bs, tid);
    __syncthreads();                 // Bs(Wn) ready
    mfma8(a, Bs, acc, lrow, kgrp);
    const int c0 = lane & 15;
    const int rg = (lane >> 4) * 4;
    const int li = wv * 4 + (lane >> 4);
#pragma unroll
    for (int nt = 0; nt < 8; ++nt) {
        float s = 0.f, q = 0.f;
#pragma unroll
        for (int r = 0; r < 4; ++r) {
            const float v = acc[nt][r];
            out[(size_t)(arow + m0 + rg + r) * D + nt * 16 + c0] = v;
            s += v; q += v * v;
        }
        ls[0][li][nt * 16 + c0] = s;
        ls[1][li][nt * 16 + c0] = q;
    }
    __syncthreads();
    if (tid < 128) {
        const int g0 = arow / NPG;
        const int gsplit = (g0 + 1) * NPG - arow;  // rows in g0; %4==0
        float s0 = 0.f, q0 = 0.f, s1 = 0.f, q1 = 0.f;
#pragma unroll
        for (int i = 0; i < 16; ++i) {
            const float sv = ls[0][i][tid];
            const float qv = ls[1][i][tid];
            if (i * 4 >= gsplit) { s1 += sv; q1 += qv; }
            else { s0 += sv; q0 += qv; }
        }
        const int rep = blockIdx.x & (REP - 1);
        float* S = &statsR[(size_t)rep * (2 * GG * D) + 0 * GG * D + g0 * D + tid];
        float* Q = &statsR[(size_t)rep * (2 * GG * D) + 1 * GG * D + g0 * D + tid];
        atomicAdd(S, s0);
        atomicAdd(Q, q0);
        if (gsplit < 64) { atomicAdd(S + D, s1); atomicAdd(Q + D, q1); }
    }
}

// reduce the REP replicas -> statsF[2][GG][D]
__global__ __launch_bounds__(256) void reduce_k(const float* __restrict__ statsR,
                                                float* __restrict__ statsF) {
    const int idx = blockIdx.x * 256 + threadIdx.x;  // 0..2047
    float s = 0.f;
#pragma unroll
    for (int rep = 0; rep < REP; ++rep) s += statsR[rep * (2 * GG * D) + idx];
    statsF[idx] = s;
}

__global__ __launch_bounds__(256) void norm_k(float* __restrict__ out,
                                              const float* __restrict__ statsF,
                                              const float* __restrict__ gamma,
                                              const float* __restrict__ beta) {
    const int i4 = blockIdx.x * 256 + threadIdx.x;  // over NN*D/4
    const int row = i4 >> 5;
    const int g = row / NPG;
    const int d0 = (i4 & 31) * 4;
    float4 v = *((float4*)out + i4);
    const float4 s4 = *(const float4*)&statsF[g * D + d0];
    const float4 q4 = *(const float4*)&statsF[GG * D + g * D + d0];
    const float4 g4 = *(const float4*)&gamma[d0];
    const float4 b4 = *(const float4*)&beta[d0];
    const float inv = 1.f / (float)NPG;
    const float invm1 = 1.f / (float)(NPG - 1);
    float mu, var, sg;
    mu = s4.x * inv; var = (q4.x - s4.x * mu) * invm1; sg = sqrtf(fmaxf(var, 0.f));
    v.x = (v.x - mu) / (sg + 1e-6f) * g4.x + b4.x;
    mu = s4.y * inv; var = (q4.y - s4.y * mu) * invm1; sg = sqrtf(fmaxf(var, 0.f));
    v.y = (v.y - mu) / (sg + 1e-6f) * g4.y + b4.y;
    mu = s4.z * inv; var = (q4.z - s4.z * mu) * invm1; sg = sqrtf(fmaxf(var, 0.f));
    v.z = (v.z - mu) / (sg + 1e-6f) * g4.z + b4.z;
    mu = s4.w * inv; var = (q4.w - s4.w * mu) * invm1; sg = sqrtf(fmaxf(var, 0.f));
    v.w = (v.w - mu) / (sg + 1e-6f) * g4.w + b4.w;
    *((float4*)out + i4) = v;
}

extern "C" void kernel_launch(void* const* d_in, const int* in_sizes, int n_in,
                              void* d_out, int out_size, void* d_ws, size_t ws_size,
                              hipStream_t stream) {
    const float* x = (const float*)d_in[0];
    const int* ei = (const int*)d_in[1];
    const float* w = (const float*)d_in[2];
    const float* W1 = (const float*)d_in[5];
    const float* W2 = (const float*)d_in[6];
    const float* Wo = (const float*)d_in[7];
    const float* Wn = (const float*)d_in[8];
    const float* gamma = (const float*)d_in[9];
    const float* beta = (const float*)d_in[10];
    float* out = (float*)d_out;

    char* ws = (char*)d_ws;
    const size_t BF16MAT = (size_t)NN * D * 2;        // 10,240,000
    size_t off = 0;
    ushort* h = (ushort*)(ws + off);      off += BF16MAT;
    ushort* xnact = (ushort*)(ws + off);  off += BF16MAT;
    const size_t ZOFF = off;                                  // zero region
    float* statsR = (float*)(ws + off);   off += (size_t)REP * 2 * GG * D * 4;  // 262,144
    float* statsF = (float*)(ws + off);   off += 2 * GG * D * 4;                // 8,192
    int* deg4 = (int*)(ws + off);         off += (size_t)NN * 4 * 4;            // 640,000
    int* ov = (int*)(ws + off);           off += (1 + OVCAP) * 4;               // 16,384
    const int ZLEN16 = (int)((off - ZOFF) / 16);              // 57,920
    short* WT = (short*)(ws + off);       off += 4 * (size_t)D * D * 2;         // 131,072
    int2* csr = (int2*)(ws + off);        // NN*64*8 = 20,480,000; total ~42 MB

    prep_k<<<4 + (ZLEN16 + 255) / 256, 256, 0, stream>>>(W1, W2, Wo, Wn, WT,
                                                         (uint4*)(ws + ZOFF), ZLEN16);
    // MLP (625 blocks) || CSR fill (625 blocks) — independent inputs
    mlpfill_k<<<2 * (NN / 64), 256, 0, stream>>>(x, WT, WT + D * D, h,
                                                 ei, w, deg4, csr, ov);
    gather_k<<<NN / 16, 256, 0, stream>>>(h, deg4, csr, ei, w, ov, xnact);
    mmstats_k<<<NN / 64, 256, 0, stream>>>(h, WT + 2 * D * D, xnact, WT + 3 * D * D, out, statsR);
    reduce_k<<<(2 * GG * D) / 256, 256, 0, stream>>>(statsR, statsF);
    norm_k<<<(NN * D / 4) / 256, 256, 0, stream>>>(out, statsF, gamma, beta);
}